// Round 1
// baseline (315.248 us; speedup 1.0000x reference)
//
#include <hip/hip_runtime.h>
#include <hip/hip_bf16.h>
#include <cstdint>
#include <cstddef>

typedef __bf16 bf16;
typedef __attribute__((ext_vector_type(4))) float f32x4;
typedef __attribute__((ext_vector_type(8))) __bf16 bf16x8;
typedef __attribute__((ext_vector_type(4))) __bf16 bf16x4;

#define D_MODEL 1024
#define NHEADS  16
#define DHEAD   64
#define SEQ     2048
#define BATCH   2
#define MROWS   (BATCH*SEQ)   /* 4096 */
#define BHTOT   (BATCH*NHEADS) /* 32 */

// 0.125 (1/sqrt(64)) * log2(e): fold into q so softmax uses exp2
#define QSCALE 0.18033688011112042f

__device__ __forceinline__ void gload16(const bf16* g, bf16* l) {
  __builtin_amdgcn_global_load_lds(
      (const __attribute__((address_space(1))) void*)g,
      (__attribute__((address_space(3))) void*)l, 16, 0, 0);
}

__device__ __forceinline__ f32x4 mfma16(bf16x8 a, bf16x8 b, f32x4 c) {
  return __builtin_amdgcn_mfma_f32_16x16x32_bf16(a, b, c, 0, 0, 0);
}

// ---------------- prep kernels ----------------

__global__ void cast_f32_bf16(const float* __restrict__ in, bf16* __restrict__ out, int n4) {
  int i = blockIdx.x * blockDim.x + threadIdx.x;
  if (i >= n4) return;
  float4 v = ((const float4*)in)[i];
  bf16x4 o;
  o[0] = (bf16)v.x; o[1] = (bf16)v.y; o[2] = (bf16)v.z; o[3] = (bf16)v.w;
  ((bf16x4*)out)[i] = o;
}

// in [R][C] fp32  ->  out [C][R] bf16
__global__ void tcast(const float* __restrict__ in, bf16* __restrict__ out, int R, int C) {
  __shared__ float t[32][33];
  int c0 = blockIdx.x * 32, r0 = blockIdx.y * 32;
  int tx = threadIdx.x, ty = threadIdx.y;
  #pragma unroll
  for (int i = 0; i < 4; i++)
    t[ty + i*8][tx] = in[(size_t)(r0 + ty + i*8) * C + c0 + tx];
  __syncthreads();
  #pragma unroll
  for (int i = 0; i < 4; i++)
    out[(size_t)(c0 + ty + i*8) * R + r0 + tx] = (bf16)t[tx][ty + i*8];
}

// v [BH][SEQ][64] bf16 -> vt [BH][64][SEQ] bf16
__global__ void transpose_v(const bf16* __restrict__ v, bf16* __restrict__ vt) {
  __shared__ bf16 t[32][33];
  int bh = blockIdx.z;
  int r0 = blockIdx.x * 32;   // kv row
  int d0 = blockIdx.y * 32;   // head dim
  int tx = threadIdx.x, ty = threadIdx.y;
  const bf16* src = v + (size_t)bh * SEQ * DHEAD;
  bf16*       dst = vt + (size_t)bh * DHEAD * SEQ;
  #pragma unroll
  for (int i = 0; i < 4; i++)
    t[ty + i*8][tx] = src[(size_t)(r0 + ty + i*8) * DHEAD + d0 + tx];
  __syncthreads();
  #pragma unroll
  for (int i = 0; i < 4; i++)
    dst[(size_t)(d0 + ty + i*8) * SEQ + r0 + tx] = t[tx][ty + i*8];
}

// ---------------- GEMM: C[M][N] = A[M][K](bf16) * Bt[N][K](bf16)^T ----------------
// EPI 0: scatter q/k/v head-major (q scaled by QSCALE)
// EPI 1: out fp32 = acc + x (residual)

template <int EPI>
__global__ __launch_bounds__(256) void gemm_bt(
    const bf16* __restrict__ A, const bf16* __restrict__ Bt, int K, int N,
    bf16* __restrict__ qb, bf16* __restrict__ kb, bf16* __restrict__ vb,
    const float* __restrict__ xres, float* __restrict__ outf) {
  __shared__ alignas(16) bf16 As[128 * 32];
  __shared__ alignas(16) bf16 Bs[128 * 32];
  const int tid = threadIdx.x;
  const int wave = tid >> 6, lane = tid & 63;
  const int wr = wave >> 1, wc = wave & 1;
  const int m0 = blockIdx.y * 128, n0 = blockIdx.x * 128;
  const int srow = lane >> 2, scol = (lane & 3) * 8;
  const int lr16 = lane & 15, lg = lane >> 4;

  f32x4 acc[4][4];
  #pragma unroll
  for (int m = 0; m < 4; m++)
    #pragma unroll
    for (int n = 0; n < 4; n++) acc[m][n] = (f32x4)0.0f;

  for (int k0 = 0; k0 < K; k0 += 32) {
    #pragma unroll
    for (int i = 0; i < 2; i++) {
      const int c = i * 4 + wave;
      gload16(A  + (size_t)(m0 + c*16 + srow) * K + k0 + scol, &As[c * 512]);
      gload16(Bt + (size_t)(n0 + c*16 + srow) * K + k0 + scol, &Bs[c * 512]);
    }
    __syncthreads();
    bf16x8 af[4], bfr[4];
    #pragma unroll
    for (int m = 0; m < 4; m++)
      af[m] = *(const bf16x8*)&As[(wr*64 + m*16 + lr16) * 32 + lg * 8];
    #pragma unroll
    for (int n = 0; n < 4; n++)
      bfr[n] = *(const bf16x8*)&Bs[(wc*64 + n*16 + lr16) * 32 + lg * 8];
    #pragma unroll
    for (int m = 0; m < 4; m++)
      #pragma unroll
      for (int n = 0; n < 4; n++)
        acc[m][n] = mfma16(af[m], bfr[n], acc[m][n]);
    __syncthreads();
  }

  #pragma unroll
  for (int n = 0; n < 4; n++) {
    const int colg = n0 + wc*64 + n*16 + lr16;
    if (EPI == 0) {
      const int which = colg >> 10;           // 0=q 1=k 2=v
      const int win = colg & 1023;
      const int h = win >> 6, d = win & 63;
      bf16* dst = (which == 0) ? qb : (which == 1) ? kb : vb;
      const float sc = (which == 0) ? QSCALE : 1.0f;
      #pragma unroll
      for (int m = 0; m < 4; m++) {
        const int rowg0 = m0 + wr*64 + m*16 + lg*4;
        #pragma unroll
        for (int j = 0; j < 4; j++) {
          const int rowg = rowg0 + j;
          const int b = rowg >> 11, r = rowg & 2047;
          dst[((size_t)((b << 4) + h) * SEQ + r) * DHEAD + d] = (bf16)(acc[m][n][j] * sc);
        }
      }
    } else {
      #pragma unroll
      for (int m = 0; m < 4; m++) {
        const int rowg0 = m0 + wr*64 + m*16 + lg*4;
        #pragma unroll
        for (int j = 0; j < 4; j++) {
          const size_t idx = (size_t)(rowg0 + j) * N + colg;
          outf[idx] = acc[m][n][j] + xres[idx];
        }
      }
    }
  }
}

// ---------------- flash attention ----------------
// q,k: [BH][SEQ][64] (q pre-scaled by QSCALE), vt: [BH][64][SEQ], o: [B][SEQ][D_MODEL] bf16
__global__ __launch_bounds__(256) void attn_kernel(
    const bf16* __restrict__ q, const bf16* __restrict__ k,
    const bf16* __restrict__ vt, bf16* __restrict__ o) {
  __shared__ alignas(16) bf16 P[4][16 * 40];  // per-wave P tile, padded stride 40
  const int tid = threadIdx.x;
  const int wave = tid >> 6, lane = tid & 63;
  const int lr16 = lane & 15, lg = lane >> 4;
  const int bh = blockIdx.y;
  const int b = bh >> 4, h = bh & 15;
  const int qr = blockIdx.x * 64 + wave * 16;
  const size_t base = (size_t)bh * SEQ * DHEAD;
  const size_t vbase = (size_t)bh * DHEAD * SEQ;

  bf16x8 qf[2];
  #pragma unroll
  for (int kk = 0; kk < 2; kk++)
    qf[kk] = *(const bf16x8*)&q[base + (size_t)(qr + lr16) * DHEAD + kk*32 + lg*8];

  float mr[4], lr[4];
  f32x4 acc[4];
  #pragma unroll
  for (int j = 0; j < 4; j++) { mr[j] = -INFINITY; lr[j] = 0.0f; }
  #pragma unroll
  for (int db = 0; db < 4; db++) acc[db] = (f32x4)0.0f;

  bf16* pw = &P[wave][0];

  for (int kv0 = 0; kv0 < SEQ; kv0 += 32) {
    f32x4 s[2];
    #pragma unroll
    for (int kvb = 0; kvb < 2; kvb++) {
      const size_t krow = base + (size_t)(kv0 + kvb*16 + lr16) * DHEAD;
      bf16x8 kf0 = *(const bf16x8*)&k[krow + lg * 8];
      bf16x8 kf1 = *(const bf16x8*)&k[krow + 32 + lg * 8];
      f32x4 z = (f32x4)0.0f;
      z = mfma16(qf[0], kf0, z);
      z = mfma16(qf[1], kf1, z);
      s[kvb] = z;
    }
    // online softmax (rows j of this 16-lane group; scores are in log2 units)
    #pragma unroll
    for (int j = 0; j < 4; j++) {
      float mx = fmaxf(s[0][j], s[1][j]);
      #pragma unroll
      for (int t = 1; t < 16; t <<= 1) mx = fmaxf(mx, __shfl_xor(mx, t));
      const float mnew = fmaxf(mr[j], mx);
      const float corr = exp2f(mr[j] - mnew);
      const float p0 = exp2f(s[0][j] - mnew);
      const float p1 = exp2f(s[1][j] - mnew);
      float rs = p0 + p1;
      #pragma unroll
      for (int t = 1; t < 16; t <<= 1) rs += __shfl_xor(rs, t);
      lr[j] = lr[j] * corr + rs;
      mr[j] = mnew;
      #pragma unroll
      for (int db = 0; db < 4; db++) acc[db][j] *= corr;
      s[0][j] = p0; s[1][j] = p1;
    }
    // P -> LDS (bf16), then re-read as MFMA A-fragment
    #pragma unroll
    for (int j = 0; j < 4; j++) {
      const int row = lg * 4 + j;
      pw[row * 40 + lr16]      = (bf16)s[0][j];
      pw[row * 40 + 16 + lr16] = (bf16)s[1][j];
    }
    bf16x8 pf = *(const bf16x8*)&pw[lr16 * 40 + lg * 8];
    #pragma unroll
    for (int db = 0; db < 4; db++) {
      bf16x8 vf = *(const bf16x8*)&vt[vbase + (size_t)(db*16 + lr16) * SEQ + kv0 + lg * 8];
      acc[db] = mfma16(pf, vf, acc[db]);
    }
  }

  // epilogue: normalize, merge heads -> o[b][row][h*64+d]
  #pragma unroll
  for (int db = 0; db < 4; db++) {
    #pragma unroll
    for (int j = 0; j < 4; j++) {
      const int row = lg * 4 + j;
      const float val = acc[db][j] / lr[j];
      o[((size_t)(b * SEQ + qr + row)) * D_MODEL + h*64 + db*16 + lr16] = (bf16)val;
    }
  }
}

// ---------------- launch ----------------

extern "C" void kernel_launch(void* const* d_in, const int* in_sizes, int n_in,
                              void* d_out, int out_size, void* d_ws, size_t ws_size,
                              hipStream_t stream) {
  const float* x      = (const float*)d_in[0];
  const float* w_qkv  = (const float*)d_in[1];
  const float* w_proj = (const float*)d_in[2];
  float* outf = (float*)d_out;

  bf16* xb    = (bf16*)d_ws;                                 // 4096*1024
  bf16* wqkvT = xb    + (size_t)MROWS * D_MODEL;             // 3072*1024
  bf16* wpT   = wqkvT + (size_t)3 * D_MODEL * D_MODEL;       // 1024*1024
  bf16* qb    = wpT   + (size_t)D_MODEL * D_MODEL;           // 32*2048*64
  bf16* kb    = qb    + (size_t)BHTOT * SEQ * DHEAD;
  bf16* vb    = kb    + (size_t)BHTOT * SEQ * DHEAD;
  bf16* vt    = xb;   // alias: xb dead after GEMM1
  bf16* ob    = vb;   // alias: vb dead after transpose_v

  dim3 tb(32, 8);

  cast_f32_bf16<<<(MROWS * D_MODEL / 4 + 255) / 256, 256, 0, stream>>>(
      x, xb, MROWS * D_MODEL / 4);
  tcast<<<dim3(3 * D_MODEL / 32, D_MODEL / 32), tb, 0, stream>>>(
      w_qkv, wqkvT, D_MODEL, 3 * D_MODEL);
  tcast<<<dim3(D_MODEL / 32, D_MODEL / 32), tb, 0, stream>>>(
      w_proj, wpT, D_MODEL, D_MODEL);

  gemm_bt<0><<<dim3(3 * D_MODEL / 128, MROWS / 128), 256, 0, stream>>>(
      xb, wqkvT, D_MODEL, 3 * D_MODEL, qb, kb, vb, nullptr, nullptr);

  transpose_v<<<dim3(SEQ / 32, DHEAD / 32, BHTOT), tb, 0, stream>>>(vb, vt);

  attn_kernel<<<dim3(SEQ / 64, BHTOT), 256, 0, stream>>>(qb, kb, vt, ob);

  gemm_bt<1><<<dim3(D_MODEL / 128, MROWS / 128), 256, 0, stream>>>(
      ob, wpT, D_MODEL, D_MODEL, nullptr, nullptr, nullptr, x, outf);
}

// Round 2
// 311.991 us; speedup vs baseline: 1.0104x; 1.0104x over previous
//
#include <hip/hip_runtime.h>
#include <hip/hip_bf16.h>
#include <cstdint>
#include <cstddef>

typedef __bf16 bf16;
typedef __attribute__((ext_vector_type(4))) float f32x4;
typedef __attribute__((ext_vector_type(8))) __bf16 bf16x8;
typedef __attribute__((ext_vector_type(4))) __bf16 bf16x4;

#define D_MODEL 1024
#define NHEADS  16
#define DHEAD   64
#define SEQ     2048
#define BATCH   2
#define MROWS   (BATCH*SEQ)   /* 4096 */
#define BHTOT   (BATCH*NHEADS) /* 32 */

// 0.125 (1/sqrt(64)) * log2(e): fold into q so softmax uses exp2
#define QSCALE 0.18033688011112042f

__device__ __forceinline__ void gload16(const bf16* g, bf16* l) {
  __builtin_amdgcn_global_load_lds(
      (const __attribute__((address_space(1))) void*)g,
      (__attribute__((address_space(3))) void*)l, 16, 0, 0);
}

__device__ __forceinline__ f32x4 mfma16(bf16x8 a, bf16x8 b, f32x4 c) {
  return __builtin_amdgcn_mfma_f32_16x16x32_bf16(a, b, c, 0, 0, 0);
}

// ---------------- prep kernels ----------------

__global__ void cast_f32_bf16(const float* __restrict__ in, bf16* __restrict__ out, int n4) {
  int i = blockIdx.x * blockDim.x + threadIdx.x;
  if (i >= n4) return;
  float4 v = ((const float4*)in)[i];
  bf16x4 o;
  o[0] = (bf16)v.x; o[1] = (bf16)v.y; o[2] = (bf16)v.z; o[3] = (bf16)v.w;
  ((bf16x4*)out)[i] = o;
}

// in [R][C] fp32  ->  out [C][R] bf16
__global__ void tcast(const float* __restrict__ in, bf16* __restrict__ out, int R, int C) {
  __shared__ float t[32][33];
  int c0 = blockIdx.x * 32, r0 = blockIdx.y * 32;
  int tx = threadIdx.x, ty = threadIdx.y;
  #pragma unroll
  for (int i = 0; i < 4; i++)
    t[ty + i*8][tx] = in[(size_t)(r0 + ty + i*8) * C + c0 + tx];
  __syncthreads();
  #pragma unroll
  for (int i = 0; i < 4; i++)
    out[(size_t)(c0 + ty + i*8) * R + r0 + tx] = (bf16)t[tx][ty + i*8];
}

// v [BH][SEQ][64] bf16 -> vt [BH][64][SEQ] bf16
__global__ void transpose_v(const bf16* __restrict__ v, bf16* __restrict__ vt) {
  __shared__ bf16 t[32][33];
  int bh = blockIdx.z;
  int r0 = blockIdx.x * 32;   // kv row
  int d0 = blockIdx.y * 32;   // head dim
  int tx = threadIdx.x, ty = threadIdx.y;
  const bf16* src = v + (size_t)bh * SEQ * DHEAD;
  bf16*       dst = vt + (size_t)bh * DHEAD * SEQ;
  #pragma unroll
  for (int i = 0; i < 4; i++)
    t[ty + i*8][tx] = src[(size_t)(r0 + ty + i*8) * DHEAD + d0 + tx];
  __syncthreads();
  #pragma unroll
  for (int i = 0; i < 4; i++)
    dst[(size_t)(d0 + ty + i*8) * SEQ + r0 + tx] = t[tx][ty + i*8];
}

// ---------------- GEMM: C[M][N] = A[M][K](bf16) * Bt[N][K](bf16)^T ----------------
// EPI 0: scatter q/k/v head-major (q scaled by QSCALE)
// EPI 1: out fp32 = acc + x (residual)

template <int EPI>
__global__ __launch_bounds__(256) void gemm_bt(
    const bf16* __restrict__ A, const bf16* __restrict__ Bt, int K, int N,
    bf16* __restrict__ qb, bf16* __restrict__ kb, bf16* __restrict__ vb,
    const float* __restrict__ xres, float* __restrict__ outf) {
  __shared__ alignas(16) bf16 As[128 * 32];
  __shared__ alignas(16) bf16 Bs[128 * 32];
  const int tid = threadIdx.x;
  const int wave = tid >> 6, lane = tid & 63;
  const int wr = wave >> 1, wc = wave & 1;
  const int m0 = blockIdx.y * 128, n0 = blockIdx.x * 128;
  const int srow = lane >> 2, scol = (lane & 3) * 8;
  const int lr16 = lane & 15, lg = lane >> 4;

  f32x4 acc[4][4];
  #pragma unroll
  for (int m = 0; m < 4; m++)
    #pragma unroll
    for (int n = 0; n < 4; n++) acc[m][n] = (f32x4)0.0f;

  for (int k0 = 0; k0 < K; k0 += 32) {
    #pragma unroll
    for (int i = 0; i < 2; i++) {
      const int c = i * 4 + wave;
      gload16(A  + (size_t)(m0 + c*16 + srow) * K + k0 + scol, &As[c * 512]);
      gload16(Bt + (size_t)(n0 + c*16 + srow) * K + k0 + scol, &Bs[c * 512]);
    }
    __syncthreads();
    bf16x8 af[4], bfr[4];
    #pragma unroll
    for (int m = 0; m < 4; m++)
      af[m] = *(const bf16x8*)&As[(wr*64 + m*16 + lr16) * 32 + lg * 8];
    #pragma unroll
    for (int n = 0; n < 4; n++)
      bfr[n] = *(const bf16x8*)&Bs[(wc*64 + n*16 + lr16) * 32 + lg * 8];
    #pragma unroll
    for (int m = 0; m < 4; m++)
      #pragma unroll
      for (int n = 0; n < 4; n++)
        acc[m][n] = mfma16(af[m], bfr[n], acc[m][n]);
    __syncthreads();
  }

  #pragma unroll
  for (int n = 0; n < 4; n++) {
    const int colg = n0 + wc*64 + n*16 + lr16;
    if (EPI == 0) {
      const int which = colg >> 10;           // 0=q 1=k 2=v
      const int win = colg & 1023;
      const int h = win >> 6, d = win & 63;
      bf16* dst = (which == 0) ? qb : (which == 1) ? kb : vb;
      const float sc = (which == 0) ? QSCALE : 1.0f;
      #pragma unroll
      for (int m = 0; m < 4; m++) {
        const int rowg0 = m0 + wr*64 + m*16 + lg*4;
        #pragma unroll
        for (int j = 0; j < 4; j++) {
          const int rowg = rowg0 + j;
          const int b = rowg >> 11, r = rowg & 2047;
          dst[((size_t)((b << 4) + h) * SEQ + r) * DHEAD + d] = (bf16)(acc[m][n][j] * sc);
        }
      }
    } else {
      #pragma unroll
      for (int m = 0; m < 4; m++) {
        const int rowg0 = m0 + wr*64 + m*16 + lg*4;
        #pragma unroll
        for (int j = 0; j < 4; j++) {
          const size_t idx = (size_t)(rowg0 + j) * N + colg;
          outf[idx] = acc[m][n][j] + xres[idx];
        }
      }
    }
  }
}

// ---------------- flash attention (swapped-operand form) ----------------
// q,k: [BH][SEQ][64] (q pre-scaled by QSCALE), vt: [BH][64][SEQ], o: [B][SEQ][D_MODEL] bf16
//
// QK^T swapped: S^T[kv][q] = mfma(A=K rows, B=Q rows) -> col(lane&15)=q, row=kv_local.
// Each lane owns q = lane&15; its 16 scores per 64-KV tile are kv = i*16 + lg*4 + r.
// Softmax reduction over kv: 15 in-lane fmax/adds + shfl_xor(16) + shfl_xor(32).
// PV swapped: O^T[d][q] = mfma(A=V^T rows d, B=P rows q) -> acc col = q (lane-local
// rescale & normalize). P crosses LDS (per-wave, stride 80) to reach B-fragment layout.
__global__ __launch_bounds__(256) void attn_kernel(
    const bf16* __restrict__ q, const bf16* __restrict__ k,
    const bf16* __restrict__ vt, bf16* __restrict__ o) {
  __shared__ alignas(16) bf16 P[4][16 * 80];  // per-wave P tile [q=16][kv=64] stride 80
  const int tid = threadIdx.x;
  const int wave = tid >> 6, lane = tid & 63;
  const int lr16 = lane & 15, lg = lane >> 4;
  const int bh = blockIdx.y;
  const int b = bh >> 4, h = bh & 15;
  const int qr = blockIdx.x * 64 + wave * 16;
  const bf16* kh = k  + (size_t)bh * SEQ * DHEAD;
  const bf16* vh = vt + (size_t)bh * DHEAD * SEQ;

  // Q fragment (B operand: rows = q)
  const bf16* qrow = q + (size_t)bh * SEQ * DHEAD + (size_t)(qr + lr16) * DHEAD;
  bf16x8 qf[2];
  qf[0] = *(const bf16x8*)&qrow[lg * 8];
  qf[1] = *(const bf16x8*)&qrow[32 + lg * 8];

  float mr = -INFINITY, lsum = 0.0f;
  f32x4 acc[4];                 // O^T: acc[db][r] = O[q=lr16][db*16 + lg*4 + r]
  #pragma unroll
  for (int db = 0; db < 4; db++) acc[db] = (f32x4)0.0f;

  bf16* pw = &P[wave][0];

  for (int kv0 = 0; kv0 < SEQ; kv0 += 64) {
    // ---- QK^T (swapped): s[i][r] = S[kv0+i*16+lg*4+r][q=lr16]
    f32x4 s[4];
    #pragma unroll
    for (int i = 0; i < 4; i++) {
      const bf16* krow = kh + (size_t)(kv0 + i * 16 + lr16) * DHEAD;
      bf16x8 kf0 = *(const bf16x8*)&krow[lg * 8];
      bf16x8 kf1 = *(const bf16x8*)&krow[32 + lg * 8];
      f32x4 z = (f32x4)0.0f;
      z = mfma16(kf0, qf[0], z);
      z = mfma16(kf1, qf[1], z);
      s[i] = z;
    }

    // ---- V fragments issued early: latency hides under softmax VALU phase
    bf16x8 vf[4][2];
    #pragma unroll
    for (int db = 0; db < 4; db++)
      #pragma unroll
      for (int h2 = 0; h2 < 2; h2++)
        vf[db][h2] = *(const bf16x8*)&vh[(size_t)(db * 16 + lr16) * SEQ
                                         + kv0 + h2 * 32 + lg * 8];

    // ---- online softmax for q = lr16 (scores are in log2 units)
    float mx = s[0][0];
    #pragma unroll
    for (int i = 0; i < 4; i++)
      #pragma unroll
      for (int r = 0; r < 4; r++) mx = fmaxf(mx, s[i][r]);
    mx = fmaxf(mx, __shfl_xor(mx, 16));
    mx = fmaxf(mx, __shfl_xor(mx, 32));
    const float mnew = fmaxf(mr, mx);
    const float corr = exp2f(mr - mnew);
    float rs = 0.0f;
    #pragma unroll
    for (int i = 0; i < 4; i++)
      #pragma unroll
      for (int r = 0; r < 4; r++) {
        const float p = exp2f(s[i][r] - mnew);
        s[i][r] = p;
        rs += p;
      }
    rs += __shfl_xor(rs, 16);
    rs += __shfl_xor(rs, 32);
    lsum = lsum * corr + rs;
    mr = mnew;
    #pragma unroll
    for (int db = 0; db < 4; db++) acc[db] *= corr;   // lane-uniform rescale

    // ---- P -> LDS (packed b64 writes), re-read as B-fragment (rows = q)
    #pragma unroll
    for (int i = 0; i < 4; i++) {
      bf16x4 pv;
      #pragma unroll
      for (int r = 0; r < 4; r++) pv[r] = (bf16)s[i][r];
      *(bf16x4*)&pw[lr16 * 80 + i * 16 + lg * 4] = pv;
    }
    bf16x8 pf0 = *(const bf16x8*)&pw[lr16 * 80 + lg * 8];
    bf16x8 pf1 = *(const bf16x8*)&pw[lr16 * 80 + 32 + lg * 8];

    // ---- PV (swapped): acc = O^T
    #pragma unroll
    for (int db = 0; db < 4; db++) {
      acc[db] = mfma16(vf[db][0], pf0, acc[db]);
      acc[db] = mfma16(vf[db][1], pf1, acc[db]);
    }
  }

  // epilogue: normalize (lane-local), pack 4 consecutive d per store
  const float inv = 1.0f / lsum;
  bf16* orow = o + ((size_t)(b * SEQ + qr + lr16)) * D_MODEL + h * 64;
  #pragma unroll
  for (int db = 0; db < 4; db++) {
    bf16x4 ov;
    #pragma unroll
    for (int r = 0; r < 4; r++) ov[r] = (bf16)(acc[db][r] * inv);
    *(bf16x4*)&orow[db * 16 + lg * 4] = ov;
  }
}

// ---------------- launch ----------------

extern "C" void kernel_launch(void* const* d_in, const int* in_sizes, int n_in,
                              void* d_out, int out_size, void* d_ws, size_t ws_size,
                              hipStream_t stream) {
  const float* x      = (const float*)d_in[0];
  const float* w_qkv  = (const float*)d_in[1];
  const float* w_proj = (const float*)d_in[2];
  float* outf = (float*)d_out;

  bf16* xb    = (bf16*)d_ws;                                 // 4096*1024
  bf16* wqkvT = xb    + (size_t)MROWS * D_MODEL;             // 3072*1024
  bf16* wpT   = wqkvT + (size_t)3 * D_MODEL * D_MODEL;       // 1024*1024
  bf16* qb    = wpT   + (size_t)D_MODEL * D_MODEL;           // 32*2048*64
  bf16* kb    = qb    + (size_t)BHTOT * SEQ * DHEAD;
  bf16* vb    = kb    + (size_t)BHTOT * SEQ * DHEAD;
  bf16* vt    = xb;   // alias: xb dead after GEMM1
  bf16* ob    = vb;   // alias: vb dead after transpose_v

  dim3 tb(32, 8);

  cast_f32_bf16<<<(MROWS * D_MODEL / 4 + 255) / 256, 256, 0, stream>>>(
      x, xb, MROWS * D_MODEL / 4);
  tcast<<<dim3(3 * D_MODEL / 32, D_MODEL / 32), tb, 0, stream>>>(
      w_qkv, wqkvT, D_MODEL, 3 * D_MODEL);
  tcast<<<dim3(D_MODEL / 32, D_MODEL / 32), tb, 0, stream>>>(
      w_proj, wpT, D_MODEL, D_MODEL);

  gemm_bt<0><<<dim3(3 * D_MODEL / 128, MROWS / 128), 256, 0, stream>>>(
      xb, wqkvT, D_MODEL, 3 * D_MODEL, qb, kb, vb, nullptr, nullptr);

  transpose_v<<<dim3(SEQ / 32, DHEAD / 32, BHTOT), tb, 0, stream>>>(vb, vt);

  attn_kernel<<<dim3(SEQ / 64, BHTOT), 256, 0, stream>>>(qb, kb, vt, ob);

  gemm_bt<1><<<dim3(D_MODEL / 128, MROWS / 128), 256, 0, stream>>>(
      ob, wpT, D_MODEL, D_MODEL, nullptr, nullptr, nullptr, x, outf);
}

// Round 3
// 187.547 us; speedup vs baseline: 1.6809x; 1.6635x over previous
//
#include <hip/hip_runtime.h>
#include <hip/hip_bf16.h>
#include <cstdint>
#include <cstddef>

typedef __bf16 bf16;
typedef __attribute__((ext_vector_type(4))) float f32x4;
typedef __attribute__((ext_vector_type(8))) __bf16 bf16x8;
typedef __attribute__((ext_vector_type(4))) __bf16 bf16x4;

#define D_MODEL 1024
#define NHEADS  16
#define DHEAD   64
#define SEQ     2048
#define BATCH   2
#define MROWS   (BATCH*SEQ)   /* 4096 */
#define BHTOT   (BATCH*NHEADS) /* 32 */

// 0.125 (1/sqrt(64)) * log2(e): fold into q so softmax uses exp2
#define QSCALE 0.18033688011112042f

__device__ __forceinline__ void gload16(const bf16* g, bf16* l) {
  __builtin_amdgcn_global_load_lds(
      (const __attribute__((address_space(1))) void*)g,
      (__attribute__((address_space(3))) void*)l, 16, 0, 0);
}

__device__ __forceinline__ f32x4 mfma16(bf16x8 a, bf16x8 b, f32x4 c) {
  return __builtin_amdgcn_mfma_f32_16x16x32_bf16(a, b, c, 0, 0, 0);
}

// ---------------- prep kernels ----------------

__global__ void cast_f32_bf16(const float* __restrict__ in, bf16* __restrict__ out, int n4) {
  int i = blockIdx.x * blockDim.x + threadIdx.x;
  if (i >= n4) return;
  float4 v = ((const float4*)in)[i];
  bf16x4 o;
  o[0] = (bf16)v.x; o[1] = (bf16)v.y; o[2] = (bf16)v.z; o[3] = (bf16)v.w;
  ((bf16x4*)out)[i] = o;
}

// in [R][C] fp32  ->  out [C][R] bf16
__global__ void tcast(const float* __restrict__ in, bf16* __restrict__ out, int R, int C) {
  __shared__ float t[32][33];
  int c0 = blockIdx.x * 32, r0 = blockIdx.y * 32;
  int tx = threadIdx.x, ty = threadIdx.y;
  #pragma unroll
  for (int i = 0; i < 4; i++)
    t[ty + i*8][tx] = in[(size_t)(r0 + ty + i*8) * C + c0 + tx];
  __syncthreads();
  #pragma unroll
  for (int i = 0; i < 4; i++)
    out[(size_t)(c0 + ty + i*8) * R + r0 + tx] = (bf16)t[tx][ty + i*8];
}

// v [BH][SEQ][64] bf16 -> vt [BH][64][SEQ] bf16
__global__ void transpose_v(const bf16* __restrict__ v, bf16* __restrict__ vt) {
  __shared__ bf16 t[32][33];
  int bh = blockIdx.z;
  int r0 = blockIdx.x * 32;   // kv row
  int d0 = blockIdx.y * 32;   // head dim
  int tx = threadIdx.x, ty = threadIdx.y;
  const bf16* src = v + (size_t)bh * SEQ * DHEAD;
  bf16*       dst = vt + (size_t)bh * DHEAD * SEQ;
  #pragma unroll
  for (int i = 0; i < 4; i++)
    t[ty + i*8][tx] = src[(size_t)(r0 + ty + i*8) * DHEAD + d0 + tx];
  __syncthreads();
  #pragma unroll
  for (int i = 0; i < 4; i++)
    dst[(size_t)(d0 + ty + i*8) * SEQ + r0 + tx] = t[tx][ty + i*8];
}

// ---------------- GEMM: C[M][N] = A[M][K](bf16) * Bt[N][K](bf16)^T ----------------

template <int EPI>
__global__ __launch_bounds__(256) void gemm_bt(
    const bf16* __restrict__ A, const bf16* __restrict__ Bt, int K, int N,
    bf16* __restrict__ qb, bf16* __restrict__ kb, bf16* __restrict__ vb,
    const float* __restrict__ xres, float* __restrict__ outf) {
  __shared__ alignas(16) bf16 As[128 * 32];
  __shared__ alignas(16) bf16 Bs[128 * 32];
  const int tid = threadIdx.x;
  const int wave = tid >> 6, lane = tid & 63;
  const int wr = wave >> 1, wc = wave & 1;
  const int m0 = blockIdx.y * 128, n0 = blockIdx.x * 128;
  const int srow = lane >> 2, scol = (lane & 3) * 8;
  const int lr16 = lane & 15, lg = lane >> 4;

  f32x4 acc[4][4];
  #pragma unroll
  for (int m = 0; m < 4; m++)
    #pragma unroll
    for (int n = 0; n < 4; n++) acc[m][n] = (f32x4)0.0f;

  for (int k0 = 0; k0 < K; k0 += 32) {
    #pragma unroll
    for (int i = 0; i < 2; i++) {
      const int c = i * 4 + wave;
      gload16(A  + (size_t)(m0 + c*16 + srow) * K + k0 + scol, &As[c * 512]);
      gload16(Bt + (size_t)(n0 + c*16 + srow) * K + k0 + scol, &Bs[c * 512]);
    }
    __syncthreads();
    bf16x8 af[4], bfr[4];
    #pragma unroll
    for (int m = 0; m < 4; m++)
      af[m] = *(const bf16x8*)&As[(wr*64 + m*16 + lr16) * 32 + lg * 8];
    #pragma unroll
    for (int n = 0; n < 4; n++)
      bfr[n] = *(const bf16x8*)&Bs[(wc*64 + n*16 + lr16) * 32 + lg * 8];
    #pragma unroll
    for (int m = 0; m < 4; m++)
      #pragma unroll
      for (int n = 0; n < 4; n++)
        acc[m][n] = mfma16(af[m], bfr[n], acc[m][n]);
    __syncthreads();
  }

  #pragma unroll
  for (int n = 0; n < 4; n++) {
    const int colg = n0 + wc*64 + n*16 + lr16;
    if (EPI == 0) {
      const int which = colg >> 10;           // 0=q 1=k 2=v
      const int win = colg & 1023;
      const int h = win >> 6, d = win & 63;
      bf16* dst = (which == 0) ? qb : (which == 1) ? kb : vb;
      const float sc = (which == 0) ? QSCALE : 1.0f;
      #pragma unroll
      for (int m = 0; m < 4; m++) {
        const int rowg0 = m0 + wr*64 + m*16 + lg*4;
        #pragma unroll
        for (int j = 0; j < 4; j++) {
          const int rowg = rowg0 + j;
          const int b = rowg >> 11, r = rowg & 2047;
          dst[((size_t)((b << 4) + h) * SEQ + r) * DHEAD + d] = (bf16)(acc[m][n][j] * sc);
        }
      }
    } else {
      #pragma unroll
      for (int m = 0; m < 4; m++) {
        const int rowg0 = m0 + wr*64 + m*16 + lg*4;
        #pragma unroll
        for (int j = 0; j < 4; j++) {
          const size_t idx = (size_t)(rowg0 + j) * N + colg;
          outf[idx] = acc[m][n][j] + xres[idx];
        }
      }
    }
  }
}

// ---------------- flash attention (swapped operands, LDS-staged K/V) ----------------
// q,k: [BH][SEQ][64] (q pre-scaled), vt: [BH][64][SEQ], o: [B][SEQ][D_MODEL] bf16
//
// K and V^T tiles (64 rows x 64 cols bf16 = 8 KB each) are staged into LDS once per
// block via global_load_lds, double-buffered (2-phase: stage t+1, compute t, barrier).
// LDS dest is linear (gload_lds requirement); the 8-slot XOR swizzle is applied to the
// per-lane GLOBAL source column and again on the ds_read side (rule 21): slot ^= row&7.
// This makes the b128 fragment reads 2-way-conflict max (free).
__global__ __launch_bounds__(256) void attn_kernel(
    const bf16* __restrict__ q, const bf16* __restrict__ k,
    const bf16* __restrict__ vt, bf16* __restrict__ o) {
  __shared__ alignas(16) bf16 Ks[2][64 * 64];
  __shared__ alignas(16) bf16 Vs[2][64 * 64];
  __shared__ alignas(16) bf16 P[4][16 * 72];   // per-wave [q=16][kv=64] stride 72
  const int tid = threadIdx.x;
  const int wave = tid >> 6, lane = tid & 63;
  const int lr16 = lane & 15, lg = lane >> 4;
  const int bh = blockIdx.y;
  const int b = bh >> 4, h = bh & 15;
  const int qr = blockIdx.x * 64 + wave * 16;
  const bf16* kh = k  + (size_t)bh * SEQ * DHEAD;
  const bf16* vh = vt + (size_t)bh * DHEAD * SEQ;

  // staging: call c covers 8 rows (1 KB); wave w does calls {2w, 2w+1} for K and V
  const int srow = lane >> 3;                    // row within 8-row chunk
  const int scol = ((lane & 7) ^ srow) * 8;      // pre-swizzled source column (elems)
  const int c0s = wave * 2;

  // Q fragment (B operand: rows = q)
  const bf16* qrow = q + (size_t)bh * SEQ * DHEAD + (size_t)(qr + lr16) * DHEAD;
  bf16x8 qf[2];
  qf[0] = *(const bf16x8*)&qrow[lg * 8];
  qf[1] = *(const bf16x8*)&qrow[32 + lg * 8];

  float mr = -INFINITY, lsum = 0.0f;
  f32x4 acc[4];                 // O^T: acc[db][r] = O[q=lr16][db*16 + lg*4 + r]
  #pragma unroll
  for (int db = 0; db < 4; db++) acc[db] = (f32x4)0.0f;

  bf16* pw = &P[wave][0];
  const int rsw = (lr16 & 7) << 4;   // read-side byte swizzle for fragment rows

  // prologue: stage tile 0 into buf 0
  #pragma unroll
  for (int c2 = 0; c2 < 2; c2++) {
    const int c = c0s + c2;
    gload16(kh + (size_t)(c*8 + srow) * DHEAD + scol, &Ks[0][c * 512]);
    gload16(vh + (size_t)(c*8 + srow) * SEQ + scol,   &Vs[0][c * 512]);
  }
  __syncthreads();

  int buf = 0;
  for (int t = 0; t < SEQ / 64; ++t) {
    // issue next-tile staging first (overlaps with compute below)
    if (t + 1 < SEQ / 64) {
      const int kv1 = (t + 1) * 64;
      #pragma unroll
      for (int c2 = 0; c2 < 2; c2++) {
        const int c = c0s + c2;
        gload16(kh + (size_t)(kv1 + c*8 + srow) * DHEAD + scol, &Ks[buf ^ 1][c * 512]);
        gload16(vh + (size_t)(c*8 + srow) * SEQ + kv1 + scol,   &Vs[buf ^ 1][c * 512]);
      }
    }

    const char* ksb = (const char*)&Ks[buf][0];
    const char* vsb = (const char*)&Vs[buf][0];

    // ---- QK^T (swapped): s[i][r] = S[kv = i*16 + lg*4 + r][q = lr16]
    f32x4 s[4];
    #pragma unroll
    for (int i = 0; i < 4; i++) {
      const int rb = (i * 16 + lr16) * 128;
      bf16x8 kf0 = *(const bf16x8*)(ksb + rb + ((lg * 16) ^ rsw));
      bf16x8 kf1 = *(const bf16x8*)(ksb + rb + ((64 + lg * 16) ^ rsw));
      f32x4 z = (f32x4)0.0f;
      z = mfma16(kf0, qf[0], z);
      z = mfma16(kf1, qf[1], z);
      s[i] = z;
    }

    // ---- online softmax for q = lr16 (log2 units)
    float mx = s[0][0];
    #pragma unroll
    for (int i = 0; i < 4; i++)
      #pragma unroll
      for (int r = 0; r < 4; r++) mx = fmaxf(mx, s[i][r]);
    mx = fmaxf(mx, __shfl_xor(mx, 16));
    mx = fmaxf(mx, __shfl_xor(mx, 32));
    const float mnew = fmaxf(mr, mx);
    const float corr = exp2f(mr - mnew);
    float rs = 0.0f;
    #pragma unroll
    for (int i = 0; i < 4; i++)
      #pragma unroll
      for (int r = 0; r < 4; r++) {
        const float p = exp2f(s[i][r] - mnew);
        s[i][r] = p;
        rs += p;
      }
    rs += __shfl_xor(rs, 16);
    rs += __shfl_xor(rs, 32);
    lsum = lsum * corr + rs;
    mr = mnew;
    #pragma unroll
    for (int db = 0; db < 4; db++) acc[db] *= corr;   // lane-uniform rescale

    // ---- P -> LDS (stride 72: 2-way max), re-read as B-fragment (rows = q)
    #pragma unroll
    for (int i = 0; i < 4; i++) {
      bf16x4 pv;
      #pragma unroll
      for (int r = 0; r < 4; r++) pv[r] = (bf16)s[i][r];
      *(bf16x4*)&pw[lr16 * 72 + i * 16 + lg * 4] = pv;
    }
    bf16x8 pf0 = *(const bf16x8*)&pw[lr16 * 72 + lg * 8];
    bf16x8 pf1 = *(const bf16x8*)&pw[lr16 * 72 + 32 + lg * 8];

    // ---- PV (swapped): acc = O^T, V fragments from LDS
    #pragma unroll
    for (int db = 0; db < 4; db++) {
      const int rb = (db * 16 + lr16) * 128;
      bf16x8 vf0 = *(const bf16x8*)(vsb + rb + ((lg * 16) ^ rsw));
      bf16x8 vf1 = *(const bf16x8*)(vsb + rb + ((64 + lg * 16) ^ rsw));
      acc[db] = mfma16(vf0, pf0, acc[db]);
      acc[db] = mfma16(vf1, pf1, acc[db]);
    }

    __syncthreads();   // drains vmcnt (staging) + lgkm; flips buffers safely
    buf ^= 1;
  }

  // epilogue: normalize (lane-local), pack 4 consecutive d per store
  const float inv = 1.0f / lsum;
  bf16* orow = o + ((size_t)(b * SEQ + qr + lr16)) * D_MODEL + h * 64;
  #pragma unroll
  for (int db = 0; db < 4; db++) {
    bf16x4 ov;
    #pragma unroll
    for (int r = 0; r < 4; r++) ov[r] = (bf16)(acc[db][r] * inv);
    *(bf16x4*)&orow[db * 16 + lg * 4] = ov;
  }
}

// ---------------- launch ----------------

extern "C" void kernel_launch(void* const* d_in, const int* in_sizes, int n_in,
                              void* d_out, int out_size, void* d_ws, size_t ws_size,
                              hipStream_t stream) {
  const float* x      = (const float*)d_in[0];
  const float* w_qkv  = (const float*)d_in[1];
  const float* w_proj = (const float*)d_in[2];
  float* outf = (float*)d_out;

  bf16* xb    = (bf16*)d_ws;                                 // 4096*1024
  bf16* wqkvT = xb    + (size_t)MROWS * D_MODEL;             // 3072*1024
  bf16* wpT   = wqkvT + (size_t)3 * D_MODEL * D_MODEL;       // 1024*1024
  bf16* qb    = wpT   + (size_t)D_MODEL * D_MODEL;           // 32*2048*64
  bf16* kb    = qb    + (size_t)BHTOT * SEQ * DHEAD;
  bf16* vb    = kb    + (size_t)BHTOT * SEQ * DHEAD;
  bf16* vt    = xb;   // alias: xb dead after GEMM1
  bf16* ob    = vb;   // alias: vb dead after transpose_v

  dim3 tb(32, 8);

  cast_f32_bf16<<<(MROWS * D_MODEL / 4 + 255) / 256, 256, 0, stream>>>(
      x, xb, MROWS * D_MODEL / 4);
  tcast<<<dim3(3 * D_MODEL / 32, D_MODEL / 32), tb, 0, stream>>>(
      w_qkv, wqkvT, D_MODEL, 3 * D_MODEL);
  tcast<<<dim3(D_MODEL / 32, D_MODEL / 32), tb, 0, stream>>>(
      w_proj, wpT, D_MODEL, D_MODEL);

  gemm_bt<0><<<dim3(3 * D_MODEL / 128, MROWS / 128), 256, 0, stream>>>(
      xb, wqkvT, D_MODEL, 3 * D_MODEL, qb, kb, vb, nullptr, nullptr);

  transpose_v<<<dim3(SEQ / 32, DHEAD / 32, BHTOT), tb, 0, stream>>>(vb, vt);

  attn_kernel<<<dim3(SEQ / 64, BHTOT), 256, 0, stream>>>(qb, kb, vt, ob);

  gemm_bt<1><<<dim3(D_MODEL / 128, MROWS / 128), 256, 0, stream>>>(
      ob, wpT, D_MODEL, D_MODEL, nullptr, nullptr, nullptr, x, outf);
}

// Round 4
// 153.567 us; speedup vs baseline: 2.0528x; 1.2213x over previous
//
#include <hip/hip_runtime.h>
#include <hip/hip_bf16.h>
#include <cstdint>
#include <cstddef>

typedef __bf16 bf16;
typedef __attribute__((ext_vector_type(4))) float f32x4;
typedef __attribute__((ext_vector_type(8))) __bf16 bf16x8;
typedef __attribute__((ext_vector_type(4))) __bf16 bf16x4;

#define D_MODEL 1024
#define NHEADS  16
#define DHEAD   64
#define SEQ     2048
#define BATCH   2
#define MROWS   (BATCH*SEQ)   /* 4096 */
#define BHTOT   (BATCH*NHEADS) /* 32 */

// 0.125 (1/sqrt(64)) * log2(e): fold into q so softmax uses exp2
#define QSCALE 0.18033688011112042f
// defer-max threshold in log2 units (HK's THR=8 nats * log2e)
#define DEFER_THR 11.5f

__device__ __forceinline__ void gload16(const bf16* g, bf16* l) {
  __builtin_amdgcn_global_load_lds(
      (const __attribute__((address_space(1))) void*)g,
      (__attribute__((address_space(3))) void*)l, 16, 0, 0);
}

__device__ __forceinline__ f32x4 mfma16(bf16x8 a, bf16x8 b, f32x4 c) {
  return __builtin_amdgcn_mfma_f32_16x16x32_bf16(a, b, c, 0, 0, 0);
}

// ---------------- prep kernels ----------------

__global__ void cast_f32_bf16(const float* __restrict__ in, bf16* __restrict__ out, int n4) {
  int i = blockIdx.x * blockDim.x + threadIdx.x;
  if (i >= n4) return;
  float4 v = ((const float4*)in)[i];
  bf16x4 o;
  o[0] = (bf16)v.x; o[1] = (bf16)v.y; o[2] = (bf16)v.z; o[3] = (bf16)v.w;
  ((bf16x4*)out)[i] = o;
}

// in [R][C] fp32  ->  out [C][R] bf16
__global__ void tcast(const float* __restrict__ in, bf16* __restrict__ out, int R, int C) {
  __shared__ float t[32][33];
  int c0 = blockIdx.x * 32, r0 = blockIdx.y * 32;
  int tx = threadIdx.x, ty = threadIdx.y;
  #pragma unroll
  for (int i = 0; i < 4; i++)
    t[ty + i*8][tx] = in[(size_t)(r0 + ty + i*8) * C + c0 + tx];
  __syncthreads();
  #pragma unroll
  for (int i = 0; i < 4; i++)
    out[(size_t)(c0 + ty + i*8) * R + r0 + tx] = (bf16)t[tx][ty + i*8];
}

// v [BH][SEQ][64] bf16 -> vt [BH][64][SEQ] bf16
__global__ void transpose_v(const bf16* __restrict__ v, bf16* __restrict__ vt) {
  __shared__ bf16 t[32][33];
  int bh = blockIdx.z;
  int r0 = blockIdx.x * 32;   // kv row
  int d0 = blockIdx.y * 32;   // head dim
  int tx = threadIdx.x, ty = threadIdx.y;
  const bf16* src = v + (size_t)bh * SEQ * DHEAD;
  bf16*       dst = vt + (size_t)bh * DHEAD * SEQ;
  #pragma unroll
  for (int i = 0; i < 4; i++)
    t[ty + i*8][tx] = src[(size_t)(r0 + ty + i*8) * DHEAD + d0 + tx];
  __syncthreads();
  #pragma unroll
  for (int i = 0; i < 4; i++)
    dst[(size_t)(d0 + ty + i*8) * SEQ + r0 + tx] = t[tx][ty + i*8];
}

// ---------------- GEMM: C[M][N] = A[M][K](bf16) * Bt[N][K](bf16)^T ----------------

template <int EPI>
__global__ __launch_bounds__(256) void gemm_bt(
    const bf16* __restrict__ A, const bf16* __restrict__ Bt, int K, int N,
    bf16* __restrict__ qb, bf16* __restrict__ kb, bf16* __restrict__ vb,
    const float* __restrict__ xres, float* __restrict__ outf) {
  __shared__ alignas(16) bf16 As[128 * 32];
  __shared__ alignas(16) bf16 Bs[128 * 32];
  const int tid = threadIdx.x;
  const int wave = tid >> 6, lane = tid & 63;
  const int wr = wave >> 1, wc = wave & 1;
  const int m0 = blockIdx.y * 128, n0 = blockIdx.x * 128;
  const int srow = lane >> 2, scol = (lane & 3) * 8;
  const int lr16 = lane & 15, lg = lane >> 4;

  f32x4 acc[4][4];
  #pragma unroll
  for (int m = 0; m < 4; m++)
    #pragma unroll
    for (int n = 0; n < 4; n++) acc[m][n] = (f32x4)0.0f;

  for (int k0 = 0; k0 < K; k0 += 32) {
    #pragma unroll
    for (int i = 0; i < 2; i++) {
      const int c = i * 4 + wave;
      gload16(A  + (size_t)(m0 + c*16 + srow) * K + k0 + scol, &As[c * 512]);
      gload16(Bt + (size_t)(n0 + c*16 + srow) * K + k0 + scol, &Bs[c * 512]);
    }
    __syncthreads();
    bf16x8 af[4], bfr[4];
    #pragma unroll
    for (int m = 0; m < 4; m++)
      af[m] = *(const bf16x8*)&As[(wr*64 + m*16 + lr16) * 32 + lg * 8];
    #pragma unroll
    for (int n = 0; n < 4; n++)
      bfr[n] = *(const bf16x8*)&Bs[(wc*64 + n*16 + lr16) * 32 + lg * 8];
    #pragma unroll
    for (int m = 0; m < 4; m++)
      #pragma unroll
      for (int n = 0; n < 4; n++)
        acc[m][n] = mfma16(af[m], bfr[n], acc[m][n]);
    __syncthreads();
  }

  #pragma unroll
  for (int n = 0; n < 4; n++) {
    const int colg = n0 + wc*64 + n*16 + lr16;
    if (EPI == 0) {
      const int which = colg >> 10;           // 0=q 1=k 2=v
      const int win = colg & 1023;
      const int h = win >> 6, d = win & 63;
      bf16* dst = (which == 0) ? qb : (which == 1) ? kb : vb;
      const float sc = (which == 0) ? QSCALE : 1.0f;
      #pragma unroll
      for (int m = 0; m < 4; m++) {
        const int rowg0 = m0 + wr*64 + m*16 + lg*4;
        #pragma unroll
        for (int j = 0; j < 4; j++) {
          const int rowg = rowg0 + j;
          const int b = rowg >> 11, r = rowg & 2047;
          dst[((size_t)((b << 4) + h) * SEQ + r) * DHEAD + d] = (bf16)(acc[m][n][j] * sc);
        }
      }
    } else {
      #pragma unroll
      for (int m = 0; m < 4; m++) {
        const int rowg0 = m0 + wr*64 + m*16 + lg*4;
        #pragma unroll
        for (int j = 0; j < 4; j++) {
          const size_t idx = (size_t)(rowg0 + j) * N + colg;
          outf[idx] = acc[m][n][j] + xres[idx];
        }
      }
    }
  }
}

// ---------------- flash attention (8 waves, LDS-staged K/V, defer-max) ----------------
// q,k: [BH][SEQ][64] (q pre-scaled), vt: [BH][64][SEQ], o: [B][SEQ][D_MODEL] bf16
//
// 8-wave (512-thread) block covers 128 q rows; all waves share one double-buffered
// K/V stage (16 KB/tile, 2 gload_lds per wave per iter). Swapped-operand QK^T and PV
// keep softmax lane-local (q = lane&15). Defer-max: per-lane local max + __all vote;
// ~31/32 iters skip the shuffle reduce, corr exp2, and acc rescale entirely. lsum is
// a per-lane partial, reduced once after the loop.
__global__ __launch_bounds__(512, 6) void attn_kernel(
    const bf16* __restrict__ q, const bf16* __restrict__ k,
    const bf16* __restrict__ vt, bf16* __restrict__ o) {
  __shared__ alignas(16) bf16 Ks[2][64 * 64];
  __shared__ alignas(16) bf16 Vs[2][64 * 64];
  __shared__ alignas(16) bf16 P[8][16 * 72];   // per-wave [q=16][kv=64] stride 72
  const int tid = threadIdx.x;
  const int wave = tid >> 6, lane = tid & 63;
  const int lr16 = lane & 15, lg = lane >> 4;
  const int bh = blockIdx.y;
  const int b = bh >> 4, h = bh & 15;
  const int qr = blockIdx.x * 128 + wave * 16;
  const bf16* kh = k  + (size_t)bh * SEQ * DHEAD;
  const bf16* vh = vt + (size_t)bh * DHEAD * SEQ;

  // staging: chunk c = wave covers 8 rows (1 KB) of each of K and V^T
  const int srow = lane >> 3;                    // row within 8-row chunk
  const int scol = ((lane & 7) ^ srow) * 8;      // pre-swizzled source column (elems)
  const int c = wave;

  // Q fragment (B operand: rows = q)
  const bf16* qrow = q + (size_t)bh * SEQ * DHEAD + (size_t)(qr + lr16) * DHEAD;
  bf16x8 qf[2];
  qf[0] = *(const bf16x8*)&qrow[lg * 8];
  qf[1] = *(const bf16x8*)&qrow[32 + lg * 8];

  float mr = -INFINITY, lsum = 0.0f;   // lsum: per-lane partial (reduced at end)
  f32x4 acc[4];                 // O^T: acc[db][r] = O[q=lr16][db*16 + lg*4 + r]
  #pragma unroll
  for (int db = 0; db < 4; db++) acc[db] = (f32x4)0.0f;

  bf16* pw = &P[wave][0];
  const int rsw = (lr16 & 7) << 4;   // read-side byte swizzle for fragment rows

  // prologue: stage tile 0 into buf 0
  gload16(kh + (size_t)(c*8 + srow) * DHEAD + scol, &Ks[0][c * 512]);
  gload16(vh + (size_t)(c*8 + srow) * SEQ + scol,   &Vs[0][c * 512]);
  __syncthreads();

  int buf = 0;
  for (int t = 0; t < SEQ / 64; ++t) {
    // issue next-tile staging first (overlaps with compute below)
    if (t + 1 < SEQ / 64) {
      const int kv1 = (t + 1) * 64;
      gload16(kh + (size_t)(kv1 + c*8 + srow) * DHEAD + scol, &Ks[buf ^ 1][c * 512]);
      gload16(vh + (size_t)(c*8 + srow) * SEQ + kv1 + scol,   &Vs[buf ^ 1][c * 512]);
    }

    const char* ksb = (const char*)&Ks[buf][0];
    const char* vsb = (const char*)&Vs[buf][0];

    // ---- QK^T (swapped): s[i][r] = S[kv = i*16 + lg*4 + r][q = lr16]
    f32x4 s[4];
    #pragma unroll
    for (int i = 0; i < 4; i++) {
      const int rb = (i * 16 + lr16) * 128;
      bf16x8 kf0 = *(const bf16x8*)(ksb + rb + ((lg * 16) ^ rsw));
      bf16x8 kf1 = *(const bf16x8*)(ksb + rb + ((64 + lg * 16) ^ rsw));
      f32x4 z = (f32x4)0.0f;
      z = mfma16(kf0, qf[0], z);
      z = mfma16(kf1, qf[1], z);
      s[i] = z;
    }

    // ---- defer-max online softmax (log2 units), q = lr16
    float a0 = fmaxf(fmaxf(s[0][0], s[0][1]), fmaxf(s[0][2], s[0][3]));
    float a1 = fmaxf(fmaxf(s[1][0], s[1][1]), fmaxf(s[1][2], s[1][3]));
    float a2 = fmaxf(fmaxf(s[2][0], s[2][1]), fmaxf(s[2][2], s[2][3]));
    float a3 = fmaxf(fmaxf(s[3][0], s[3][1]), fmaxf(s[3][2], s[3][3]));
    const float lmax = fmaxf(fmaxf(a0, a1), fmaxf(a2, a3));

    if (!__all(lmax <= mr + DEFER_THR)) {
      float mx = lmax;
      mx = fmaxf(mx, __shfl_xor(mx, 16));
      mx = fmaxf(mx, __shfl_xor(mx, 32));
      const float mnew = fmaxf(mr, mx);
      const float corr = exp2f(mr - mnew);
      lsum *= corr;
      #pragma unroll
      for (int db = 0; db < 4; db++) acc[db] *= corr;
      mr = mnew;
    }

    #pragma unroll
    for (int i = 0; i < 4; i++)
      #pragma unroll
      for (int r = 0; r < 4; r++)
        s[i][r] = exp2f(s[i][r] - mr);
    float rs = 0.0f;
    #pragma unroll
    for (int i = 0; i < 4; i++)
      rs += (s[i][0] + s[i][1]) + (s[i][2] + s[i][3]);
    lsum += rs;

    // ---- P -> LDS (stride 72), re-read as B-fragment (rows = q)
    #pragma unroll
    for (int i = 0; i < 4; i++) {
      bf16x4 pv;
      #pragma unroll
      for (int r = 0; r < 4; r++) pv[r] = (bf16)s[i][r];
      *(bf16x4*)&pw[lr16 * 72 + i * 16 + lg * 4] = pv;
    }
    bf16x8 pf0 = *(const bf16x8*)&pw[lr16 * 72 + lg * 8];
    bf16x8 pf1 = *(const bf16x8*)&pw[lr16 * 72 + 32 + lg * 8];

    // ---- PV (swapped): acc = O^T, V fragments from LDS
    #pragma unroll
    for (int db = 0; db < 4; db++) {
      const int rb = (db * 16 + lr16) * 128;
      bf16x8 vf0 = *(const bf16x8*)(vsb + rb + ((lg * 16) ^ rsw));
      bf16x8 vf1 = *(const bf16x8*)(vsb + rb + ((64 + lg * 16) ^ rsw));
      acc[db] = mfma16(vf0, pf0, acc[db]);
      acc[db] = mfma16(vf1, pf1, acc[db]);
    }

    __syncthreads();   // drains vmcnt (staging) + lgkm; flips buffers safely
    buf ^= 1;
  }

  // epilogue: reduce lsum across the 4 lanes sharing this q row, normalize, store
  lsum += __shfl_xor(lsum, 16);
  lsum += __shfl_xor(lsum, 32);
  const float inv = 1.0f / lsum;
  bf16* orow = o + ((size_t)(b * SEQ + qr + lr16)) * D_MODEL + h * 64;
  #pragma unroll
  for (int db = 0; db < 4; db++) {
    bf16x4 ov;
    #pragma unroll
    for (int r = 0; r < 4; r++) ov[r] = (bf16)(acc[db][r] * inv);
    *(bf16x4*)&orow[db * 16 + lg * 4] = ov;
  }
}

// ---------------- launch ----------------

extern "C" void kernel_launch(void* const* d_in, const int* in_sizes, int n_in,
                              void* d_out, int out_size, void* d_ws, size_t ws_size,
                              hipStream_t stream) {
  const float* x      = (const float*)d_in[0];
  const float* w_qkv  = (const float*)d_in[1];
  const float* w_proj = (const float*)d_in[2];
  float* outf = (float*)d_out;

  bf16* xb    = (bf16*)d_ws;                                 // 4096*1024
  bf16* wqkvT = xb    + (size_t)MROWS * D_MODEL;             // 3072*1024
  bf16* wpT   = wqkvT + (size_t)3 * D_MODEL * D_MODEL;       // 1024*1024
  bf16* qb    = wpT   + (size_t)D_MODEL * D_MODEL;           // 32*2048*64
  bf16* kb    = qb    + (size_t)BHTOT * SEQ * DHEAD;
  bf16* vb    = kb    + (size_t)BHTOT * SEQ * DHEAD;
  bf16* vt    = xb;   // alias: xb dead after GEMM1
  bf16* ob    = vb;   // alias: vb dead after transpose_v

  dim3 tb(32, 8);

  cast_f32_bf16<<<(MROWS * D_MODEL / 4 + 255) / 256, 256, 0, stream>>>(
      x, xb, MROWS * D_MODEL / 4);
  tcast<<<dim3(3 * D_MODEL / 32, D_MODEL / 32), tb, 0, stream>>>(
      w_qkv, wqkvT, D_MODEL, 3 * D_MODEL);
  tcast<<<dim3(D_MODEL / 32, D_MODEL / 32), tb, 0, stream>>>(
      w_proj, wpT, D_MODEL, D_MODEL);

  gemm_bt<0><<<dim3(3 * D_MODEL / 128, MROWS / 128), 256, 0, stream>>>(
      xb, wqkvT, D_MODEL, 3 * D_MODEL, qb, kb, vb, nullptr, nullptr);

  transpose_v<<<dim3(SEQ / 32, DHEAD / 32, BHTOT), tb, 0, stream>>>(vb, vt);

  attn_kernel<<<dim3(SEQ / 128, BHTOT), 512, 0, stream>>>(qb, kb, vt, ob);

  gemm_bt<1><<<dim3(D_MODEL / 128, MROWS / 128), 256, 0, stream>>>(
      ob, wpT, D_MODEL, D_MODEL, nullptr, nullptr, nullptr, x, outf);
}

// Round 5
// 130.989 us; speedup vs baseline: 2.4067x; 1.1724x over previous
//
#include <hip/hip_runtime.h>
#include <hip/hip_bf16.h>
#include <cstdint>
#include <cstddef>

typedef __bf16 bf16;
typedef __attribute__((ext_vector_type(4))) float f32x4;
typedef __attribute__((ext_vector_type(8))) __bf16 bf16x8;
typedef __attribute__((ext_vector_type(4))) __bf16 bf16x4;

#define D_MODEL 1024
#define NHEADS  16
#define DHEAD   64
#define SEQ     2048
#define BATCH   2
#define MROWS   (BATCH*SEQ)   /* 4096 */
#define BHTOT   (BATCH*NHEADS) /* 32 */

// 0.125 (1/sqrt(64)) * log2(e): fold into q so softmax uses exp2
#define QSCALE 0.18033688011112042f
// defer-max threshold in log2 units (HK's THR=8 nats * log2e)
#define DEFER_THR 11.5f

__device__ __forceinline__ void gload16(const bf16* g, bf16* l) {
  __builtin_amdgcn_global_load_lds(
      (const __attribute__((address_space(1))) void*)g,
      (__attribute__((address_space(3))) void*)l, 16, 0, 0);
}

__device__ __forceinline__ f32x4 mfma16(bf16x8 a, bf16x8 b, f32x4 c) {
  return __builtin_amdgcn_mfma_f32_16x16x32_bf16(a, b, c, 0, 0, 0);
}

// raw v_exp_f32 (skip libm range-fixup; |x| well within range here)
__device__ __forceinline__ float fexp2(float x) {
#if __has_builtin(__builtin_amdgcn_exp2f)
  return __builtin_amdgcn_exp2f(x);
#else
  float r; asm("v_exp_f32 %0, %1" : "=v"(r) : "v"(x)); return r;
#endif
}

// ---------------- prep kernels ----------------

__global__ void cast_f32_bf16(const float* __restrict__ in, bf16* __restrict__ out, int n4) {
  int i = blockIdx.x * blockDim.x + threadIdx.x;
  if (i >= n4) return;
  float4 v = ((const float4*)in)[i];
  bf16x4 o;
  o[0] = (bf16)v.x; o[1] = (bf16)v.y; o[2] = (bf16)v.z; o[3] = (bf16)v.w;
  ((bf16x4*)out)[i] = o;
}

// in [R][C] fp32  ->  out [C][R] bf16
__global__ void tcast(const float* __restrict__ in, bf16* __restrict__ out, int R, int C) {
  __shared__ float t[32][33];
  int c0 = blockIdx.x * 32, r0 = blockIdx.y * 32;
  int tx = threadIdx.x, ty = threadIdx.y;
  #pragma unroll
  for (int i = 0; i < 4; i++)
    t[ty + i*8][tx] = in[(size_t)(r0 + ty + i*8) * C + c0 + tx];
  __syncthreads();
  #pragma unroll
  for (int i = 0; i < 4; i++)
    out[(size_t)(c0 + ty + i*8) * R + r0 + tx] = (bf16)t[tx][ty + i*8];
}

// v [BH][SEQ][64] bf16 -> vt [BH][64][SEQ] bf16
__global__ void transpose_v(const bf16* __restrict__ v, bf16* __restrict__ vt) {
  __shared__ bf16 t[32][33];
  int bh = blockIdx.z;
  int r0 = blockIdx.x * 32;   // kv row
  int d0 = blockIdx.y * 32;   // head dim
  int tx = threadIdx.x, ty = threadIdx.y;
  const bf16* src = v + (size_t)bh * SEQ * DHEAD;
  bf16*       dst = vt + (size_t)bh * DHEAD * SEQ;
  #pragma unroll
  for (int i = 0; i < 4; i++)
    t[ty + i*8][tx] = src[(size_t)(r0 + ty + i*8) * DHEAD + d0 + tx];
  __syncthreads();
  #pragma unroll
  for (int i = 0; i < 4; i++)
    dst[(size_t)(d0 + ty + i*8) * SEQ + r0 + tx] = t[tx][ty + i*8];
}

// ---------------- GEMM: C[M][N] = A[M][K](bf16) * Bt[N][K](bf16)^T ----------------
// BK=64, XOR-swizzled LDS (pre-swizzled global source + swizzled ds_read, rule 21).
// EPI 0: scatter q/k/v head-major (q scaled by QSCALE); EPI 1: fp32 out = acc + x.

template <int EPI>
__global__ __launch_bounds__(256, 3) void gemm_bt(
    const bf16* __restrict__ A, const bf16* __restrict__ Bt, int K, int N,
    bf16* __restrict__ qb, bf16* __restrict__ kb, bf16* __restrict__ vb,
    const float* __restrict__ xres, float* __restrict__ outf) {
  __shared__ alignas(16) bf16 As[128 * 64];
  __shared__ alignas(16) bf16 Bs[128 * 64];
  const int tid = threadIdx.x;
  const int wave = tid >> 6, lane = tid & 63;
  const int wr = wave >> 1, wc = wave & 1;
  const int m0 = blockIdx.y * 128, n0 = blockIdx.x * 128;
  const int srow = lane >> 3;                    // row within 8-row chunk
  const int scol = ((lane & 7) ^ srow) * 8;      // pre-swizzled source column
  const int lr16 = lane & 15, lg = lane >> 4;
  const int rsw = (lr16 & 7) << 4;
  const int cA = (lg * 16) ^ rsw;
  const int cB = (64 + lg * 16) ^ rsw;
  const char* aP = (const char*)As + (wr*64 + lr16) * 128;
  const char* bP = (const char*)Bs + (wc*64 + lr16) * 128;

  f32x4 acc[4][4];
  #pragma unroll
  for (int m = 0; m < 4; m++)
    #pragma unroll
    for (int n = 0; n < 4; n++) acc[m][n] = (f32x4)0.0f;

  for (int k0 = 0; k0 < K; k0 += 64) {
    #pragma unroll
    for (int j = 0; j < 4; j++) {
      const int c = wave * 4 + j;                // 8-row chunk index (0..15)
      gload16(A  + (size_t)(m0 + c*8 + srow) * K + k0 + scol, &As[c * 512]);
      gload16(Bt + (size_t)(n0 + c*8 + srow) * K + k0 + scol, &Bs[c * 512]);
    }
    __syncthreads();
    bf16x8 af[4][2], bfr[4][2];
    #pragma unroll
    for (int m = 0; m < 4; m++) {
      af[m][0] = *(const bf16x8*)(aP + m*2048 + cA);
      af[m][1] = *(const bf16x8*)(aP + m*2048 + cB);
    }
    #pragma unroll
    for (int n = 0; n < 4; n++) {
      bfr[n][0] = *(const bf16x8*)(bP + n*2048 + cA);
      bfr[n][1] = *(const bf16x8*)(bP + n*2048 + cB);
    }
    #pragma unroll
    for (int m = 0; m < 4; m++)
      #pragma unroll
      for (int n = 0; n < 4; n++) {
        acc[m][n] = mfma16(af[m][0], bfr[n][0], acc[m][n]);
        acc[m][n] = mfma16(af[m][1], bfr[n][1], acc[m][n]);
      }
    __syncthreads();
  }

  #pragma unroll
  for (int n = 0; n < 4; n++) {
    const int colg = n0 + wc*64 + n*16 + lr16;
    if (EPI == 0) {
      const int which = colg >> 10;           // 0=q 1=k 2=v
      const int win = colg & 1023;
      const int h = win >> 6, d = win & 63;
      bf16* dst = (which == 0) ? qb : (which == 1) ? kb : vb;
      const float sc = (which == 0) ? QSCALE : 1.0f;
      #pragma unroll
      for (int m = 0; m < 4; m++) {
        const int rowg0 = m0 + wr*64 + m*16 + lg*4;
        #pragma unroll
        for (int j = 0; j < 4; j++) {
          const int rowg = rowg0 + j;
          const int b = rowg >> 11, r = rowg & 2047;
          dst[((size_t)((b << 4) + h) * SEQ + r) * DHEAD + d] = (bf16)(acc[m][n][j] * sc);
        }
      }
    } else {
      #pragma unroll
      for (int m = 0; m < 4; m++) {
        const int rowg0 = m0 + wr*64 + m*16 + lg*4;
        #pragma unroll
        for (int j = 0; j < 4; j++) {
          const size_t idx = (size_t)(rowg0 + j) * N + colg;
          outf[idx] = acc[m][n][j] + xres[idx];
        }
      }
    }
  }
}

// ---------------- flash attention (8 waves, LDS-staged K/V, defer-max) ----------------
// Swapped QK^T/PV keep softmax lane-local (q = lane&15). mr starts at 0 (scores are
// bounded ~|9| log2 units for this distribution; defer-rescale handles excursions).
// -mr is folded into the QK^T accumulator init, so the steady-state per-score cost is
// exactly one raw v_exp_f32. All LDS fragment pointers hoisted; 2x-unrolled dbuf loop.
__global__ __launch_bounds__(512, 4) void attn_kernel(
    const bf16* __restrict__ q, const bf16* __restrict__ k,
    const bf16* __restrict__ vt, bf16* __restrict__ o) {
  __shared__ alignas(16) bf16 Ks[2][64 * 64];
  __shared__ alignas(16) bf16 Vs[2][64 * 64];
  __shared__ alignas(16) bf16 P[8][16 * 72];   // per-wave [q=16][kv=64] stride 72
  const int tid = threadIdx.x;
  const int wave = tid >> 6, lane = tid & 63;
  const int lr16 = lane & 15, lg = lane >> 4;
  const int bh = blockIdx.y;
  const int b = bh >> 4, h = bh & 15;
  const int qr = blockIdx.x * 128 + wave * 16;
  const bf16* kh = k  + (size_t)bh * SEQ * DHEAD;
  const bf16* vh = vt + (size_t)bh * DHEAD * SEQ;

  // staging: chunk c = wave covers 8 rows (1 KB) of each of K and V^T
  const int srow = lane >> 3;
  const int scol = ((lane & 7) ^ srow) * 8;
  const bf16* kg = kh + (size_t)(wave*8 + srow) * DHEAD + scol;
  const bf16* vg = vh + (size_t)(wave*8 + srow) * SEQ + scol;
  bf16* ldsK0 = &Ks[0][wave * 512];
  bf16* ldsK1 = &Ks[1][wave * 512];
  bf16* ldsV0 = &Vs[0][wave * 512];
  bf16* ldsV1 = &Vs[1][wave * 512];

  // Q fragment (B operand: rows = q)
  const bf16* qrow = q + (size_t)bh * SEQ * DHEAD + (size_t)(qr + lr16) * DHEAD;
  bf16x8 qf[2];
  qf[0] = *(const bf16x8*)&qrow[lg * 8];
  qf[1] = *(const bf16x8*)&qrow[32 + lg * 8];

  float mr = 0.0f, lsum = 0.0f;   // lsum: per-lane partial (reduced at end)
  f32x4 acc[4];                   // O^T: acc[db][r] = O[q=lr16][db*16 + lg*4 + r]
  #pragma unroll
  for (int db = 0; db < 4; db++) acc[db] = (f32x4)0.0f;

  // hoisted LDS pointers (loop-invariant; reads use imm offsets)
  const int rsw = (lr16 & 7) << 4;
  const int cA = (lg * 16) ^ rsw;
  const int cB = (64 + lg * 16) ^ rsw;
  const char* kr0 = (const char*)&Ks[0][0] + lr16 * 128;
  const char* kr1 = (const char*)&Ks[1][0] + lr16 * 128;
  const char* vr0 = (const char*)&Vs[0][0] + lr16 * 128;
  const char* vr1 = (const char*)&Vs[1][0] + lr16 * 128;
  bf16* pww = &P[wave][lr16 * 72 + lg * 4];         // write: +i*16 elems
  const bf16* pfr = &P[wave][lr16 * 72 + lg * 8];   // read: +0 / +32 elems

  auto compute = [&](const char* kr, const char* vr) {
    // ---- QK^T (swapped), C-init = -mr folds the max-shift into the MFMA
    const float nmr = -mr;
    f32x4 s[4];
    __builtin_amdgcn_s_setprio(1);
    #pragma unroll
    for (int i = 0; i < 4; i++) {
      bf16x8 kf0 = *(const bf16x8*)(kr + i*2048 + cA);
      bf16x8 kf1 = *(const bf16x8*)(kr + i*2048 + cB);
      f32x4 z = {nmr, nmr, nmr, nmr};
      z = mfma16(kf0, qf[0], z);
      z = mfma16(kf1, qf[1], z);
      s[i] = z;
    }
    __builtin_amdgcn_s_setprio(0);

    // ---- defer-max check (max3-fused tree)
    float u0 = fmaxf(fmaxf(s[0][0], s[0][1]), s[0][2]);
    float u1 = fmaxf(fmaxf(s[0][3], s[1][0]), s[1][1]);
    float u2 = fmaxf(fmaxf(s[1][2], s[1][3]), s[2][0]);
    float u3 = fmaxf(fmaxf(s[2][1], s[2][2]), s[2][3]);
    float u4 = fmaxf(fmaxf(s[3][0], s[3][1]), s[3][2]);
    float lmax = fmaxf(fmaxf(fmaxf(u0, u1), fmaxf(u2, u3)), fmaxf(u4, s[3][3]));

    if (!__all(lmax <= DEFER_THR)) {       // rare: rescale
      float mx = fmaxf(lmax, __shfl_xor(lmax, 16));
      mx = fmaxf(mx, __shfl_xor(mx, 32));
      mx = fmaxf(mx, 0.0f);
      const float corr = fexp2(-mx);
      lsum *= corr;
      #pragma unroll
      for (int db = 0; db < 4; db++) acc[db] *= corr;
      mr += mx;
      #pragma unroll
      for (int i = 0; i < 4; i++)
        #pragma unroll
        for (int r = 0; r < 4; r++) s[i][r] -= mx;
    }

    // ---- p = exp2(shifted score); per-lane partial sum
    #pragma unroll
    for (int i = 0; i < 4; i++)
      #pragma unroll
      for (int r = 0; r < 4; r++) s[i][r] = fexp2(s[i][r]);
    lsum += ((s[0][0] + s[0][1]) + (s[0][2] + s[0][3]))
          + ((s[1][0] + s[1][1]) + (s[1][2] + s[1][3]))
          + ((s[2][0] + s[2][1]) + (s[2][2] + s[2][3]))
          + ((s[3][0] + s[3][1]) + (s[3][2] + s[3][3]));

    // ---- P -> LDS (even-spread stride 72), re-read as B-fragment
    #pragma unroll
    for (int i = 0; i < 4; i++) {
      bf16x4 pv;
      #pragma unroll
      for (int r = 0; r < 4; r++) pv[r] = (bf16)s[i][r];
      *(bf16x4*)(pww + i * 16) = pv;
    }
    bf16x8 pf0 = *(const bf16x8*)pfr;
    bf16x8 pf1 = *(const bf16x8*)(pfr + 32);

    // ---- PV (swapped): acc = O^T
    __builtin_amdgcn_s_setprio(1);
    #pragma unroll
    for (int db = 0; db < 4; db++) {
      bf16x8 vf0 = *(const bf16x8*)(vr + db*2048 + cA);
      bf16x8 vf1 = *(const bf16x8*)(vr + db*2048 + cB);
      acc[db] = mfma16(vf0, pf0, acc[db]);
      acc[db] = mfma16(vf1, pf1, acc[db]);
    }
    __builtin_amdgcn_s_setprio(0);
  };

  // prologue: stage tile 0 into buf 0
  gload16(kg, ldsK0); gload16(vg, ldsV0);
  kg += 64 * DHEAD; vg += 64;
  __syncthreads();

  for (int t = 0; t < SEQ / 64; t += 2) {
    // phase A: stage t+1 -> buf1 (always valid: t+1 <= 31), compute buf0
    gload16(kg, ldsK1); gload16(vg, ldsV1);
    kg += 64 * DHEAD; vg += 64;
    compute(kr0, vr0);
    __syncthreads();
    // phase B: stage t+2 -> buf0 (guarded), compute buf1
    if (t + 2 < SEQ / 64) {
      gload16(kg, ldsK0); gload16(vg, ldsV0);
      kg += 64 * DHEAD; vg += 64;
    }
    compute(kr1, vr1);
    __syncthreads();
  }

  // epilogue: reduce lsum across the 4 lane-groups sharing this q row
  lsum += __shfl_xor(lsum, 16);
  lsum += __shfl_xor(lsum, 32);
  const float inv = 1.0f / lsum;
  bf16* orow = o + ((size_t)(b * SEQ + qr + lr16)) * D_MODEL + h * 64;
  #pragma unroll
  for (int db = 0; db < 4; db++) {
    bf16x4 ov;
    #pragma unroll
    for (int r = 0; r < 4; r++) ov[r] = (bf16)(acc[db][r] * inv);
    *(bf16x4*)&orow[db * 16 + lg * 4] = ov;
  }
}

// ---------------- launch ----------------

extern "C" void kernel_launch(void* const* d_in, const int* in_sizes, int n_in,
                              void* d_out, int out_size, void* d_ws, size_t ws_size,
                              hipStream_t stream) {
  const float* x      = (const float*)d_in[0];
  const float* w_qkv  = (const float*)d_in[1];
  const float* w_proj = (const float*)d_in[2];
  float* outf = (float*)d_out;

  bf16* xb    = (bf16*)d_ws;                                 // 4096*1024
  bf16* wqkvT = xb    + (size_t)MROWS * D_MODEL;             // 3072*1024
  bf16* wpT   = wqkvT + (size_t)3 * D_MODEL * D_MODEL;       // 1024*1024
  bf16* qb    = wpT   + (size_t)D_MODEL * D_MODEL;           // 32*2048*64
  bf16* kb    = qb    + (size_t)BHTOT * SEQ * DHEAD;
  bf16* vb    = kb    + (size_t)BHTOT * SEQ * DHEAD;
  bf16* vt    = xb;   // alias: xb dead after GEMM1
  bf16* ob    = vb;   // alias: vb dead after transpose_v

  dim3 tb(32, 8);

  cast_f32_bf16<<<(MROWS * D_MODEL / 4 + 255) / 256, 256, 0, stream>>>(
      x, xb, MROWS * D_MODEL / 4);
  tcast<<<dim3(3 * D_MODEL / 32, D_MODEL / 32), tb, 0, stream>>>(
      w_qkv, wqkvT, D_MODEL, 3 * D_MODEL);
  tcast<<<dim3(D_MODEL / 32, D_MODEL / 32), tb, 0, stream>>>(
      w_proj, wpT, D_MODEL, D_MODEL);

  gemm_bt<0><<<dim3(3 * D_MODEL / 128, MROWS / 128), 256, 0, stream>>>(
      xb, wqkvT, D_MODEL, 3 * D_MODEL, qb, kb, vb, nullptr, nullptr);

  transpose_v<<<dim3(SEQ / 32, DHEAD / 32, BHTOT), tb, 0, stream>>>(vb, vt);

  attn_kernel<<<dim3(SEQ / 128, BHTOT), 512, 0, stream>>>(qb, kb, vt, ob);

  gemm_bt<1><<<dim3(D_MODEL / 128, MROWS / 128), 256, 0, stream>>>(
      ob, wpT, D_MODEL, D_MODEL, nullptr, nullptr, nullptr, x, outf);
}